// Round 11
// baseline (29.890 us; speedup 1.0000x reference)
//
#include <hip/hip_runtime.h>

#define VOLD 256
// Super-cell = 32(x) x 16(y) x 32(z); grid 8 x 16 x 8 = 1024 blocks.
// Each block: one scan + one weight set (wy/wz shared, wx spans 32), then TWO
// half-cell (16x) K-loops; half-A's NT stores issue before half-B's compute
// (no barrier between) so the HBM drain overlaps the second K-loop.
#define CXD 32
#define CYD 16
#define CZD 32
#define NCELLS 1024
#define CAP 72

typedef float nfloat4 __attribute__((ext_vector_type(4)));
typedef float f2 __attribute__((ext_vector_type(2)));

__global__ __launch_bounds__(256) void splat_kernel(
    const float* __restrict__ centers, const float* __restrict__ sigmas,
    const float* __restrict__ intens, float* __restrict__ vol, int N)
{
    const int cell = blockIdx.x;
    const int czc = cell & 7;            // 0..7
    const int cyc = (cell >> 3) & 15;    // 0..15
    const int cxs = cell >> 7;           // 0..7
    const int vx0 = cxs * CXD, vy0 = cyc * CYD, vz0 = czc * CZD;
    const int t = threadIdx.x;

    __shared__ int    lcnt;
    __shared__ float4 pc4[CAP];          // cx, cy, cz, sigma
    __shared__ float  pint[CAP];         // intensity
    __shared__ float  wxx[CAP][CXD];     // 32-wide x weights (intensity folded)
    __shared__ float  wy[CAP][CYD];      // shared by both halves
    __shared__ float  wz[CAP][CZD];      // shared by both halves  (~24.5 KB)

    if (t == 0) lcnt = 0;
    __syncthreads();

    // ---- Scan: 4-gaussian packs vs super-region bounds (0.5-voxel margin:
    // false positives only -> all-zero weights, harmless). ----
    const float axh = (float)(vx0 + CXD) + 0.5f, axl = (float)vx0 - 0.5f;
    const float ayh = (float)(vy0 + CYD) + 0.5f, ayl = (float)vy0 - 0.5f;
    const float azh = (float)(vz0 + CZD) + 0.5f, azl = (float)vz0 - 0.5f;

    const float4* c4 = (const float4*)centers;
    const float4* s4 = (const float4*)sigmas;
    const int npack = N >> 2;
    for (int i = t; i < npack; i += 256) {
        const float4 f0  = c4[3 * i];
        const float4 f1  = c4[3 * i + 1];
        const float4 f2v = c4[3 * i + 2];
        const float4 sg4 = s4[i];
        const float gx[4] = {f0.x, f0.w, f1.z, f2v.y};
        const float gy[4] = {f0.y, f1.x, f1.w, f2v.z};
        const float gz[4] = {f0.z, f1.y, f2v.x, f2v.w};
        const float gs[4] = {sg4.x, sg4.y, sg4.z, sg4.w};
        #pragma unroll
        for (int u = 0; u < 4; ++u) {
            const float m1 = fmaxf(fmaxf(fmaf(gx[u], 255.0f, -axh),
                                         fmaf(gy[u], 255.0f, -ayh)),
                                         fmaf(gz[u], 255.0f, -azh));
            const float m2 = fmaxf(fmaxf(fmaf(-gx[u], 255.0f, axl),
                                         fmaf(-gy[u], 255.0f, ayl)),
                                         fmaf(-gz[u], 255.0f, azl));
            if (fmaxf(m1, m2) < gs[u] * 765.0f) {
                const int p = atomicAdd(&lcnt, 1);
                if (p < CAP) {
                    pc4[p]  = make_float4(gx[u], gy[u], gz[u], gs[u]);
                    pint[p] = intens[4 * i + u];
                }
            }
        }
    }
    for (int g = (npack << 2) + t; g < N; g += 256) {   // tail, robustness
        const float cx = centers[3 * g], cy = centers[3 * g + 1], cz = centers[3 * g + 2];
        const float sg = sigmas[g];
        const float m1 = fmaxf(fmaxf(fmaf(cx, 255.0f, -axh), fmaf(cy, 255.0f, -ayh)),
                               fmaf(cz, 255.0f, -azh));
        const float m2 = fmaxf(fmaxf(fmaf(-cx, 255.0f, axl), fmaf(-cy, 255.0f, ayl)),
                               fmaf(-cz, 255.0f, azl));
        if (fmaxf(m1, m2) < sg * 765.0f) {
            const int p = atomicAdd(&lcnt, 1);
            if (p < CAP) { pc4[p] = make_float4(cx, cy, cz, sg); pint[p] = intens[g]; }
        }
    }
    __syncthreads();
    const int K = min(lcnt, CAP);

    // ---- Weights (float-domain validity == reference's floor/int logic). ----
    for (int i = t; i < K * CXD; i += 256) {
        const int g = i >> 5, o = i & 31;
        const float4 p = pc4[g];
        const float cn = p.x, sig = p.w;
        const float cv = cn * 255.0f, cut = 3.0f * sig * 255.0f;
        const float fi = (float)(vx0 + o);
        float wv = 0.0f;
        if ((fi + 1.0f > cv - cut) && (fi <= fminf(cv + cut, 255.0f))) {
            const float d = fi * (1.0f / 255.0f) - cn;
            wv = __expf(-d * d * (0.5f / (sig * sig))) * pint[g];
        }
        wxx[g][o] = wv;
    }
    for (int i = t; i < K * CYD; i += 256) {
        const int g = i >> 4, o = i & 15;
        const float4 p = pc4[g];
        const float cn = p.y, sig = p.w;
        const float cv = cn * 255.0f, cut = 3.0f * sig * 255.0f;
        const float fi = (float)(vy0 + o);
        float wv = 0.0f;
        if ((fi + 1.0f > cv - cut) && (fi <= fminf(cv + cut, 255.0f))) {
            const float d = fi * (1.0f / 255.0f) - cn;
            wv = __expf(-d * d * (0.5f / (sig * sig)));
        }
        wy[g][o] = wv;
    }
    for (int i = t; i < K * CZD; i += 256) {
        const int g = i >> 5, o = i & 31;
        const float4 p = pc4[g];
        const float cn = p.z, sig = p.w;
        const float cv = cn * 255.0f, cut = 3.0f * sig * 255.0f;
        const float fi = (float)(vz0 + o);
        float wv = 0.0f;
        if ((fi + 1.0f > cv - cut) && (fi <= fminf(cv + cut, 255.0f))) {
            const float d = fi * (1.0f / 255.0f) - cn;
            wv = __expf(-d * d * (0.5f / (sig * sig)));
        }
        wz[g][o] = wv;
    }
    __syncthreads();

    // ---- Two half-cell K-loops; NO barrier after half-A stores -> overlap. --
    const int zq = t & 7;            // z = 4*zq .. 4*zq+3
    const int xl = (t >> 3) & 15;    // x within half
    const int yh = t >> 7;           // 0/1: y in [8*yh, 8*yh+8)  (wave-uniform)

    #pragma unroll
    for (int h = 0; h < 2; ++h) {
        const int xi = 16 * h + xl;  // x within super-cell

        f2 acc[8][2];                // [yy][z-pair]
        #pragma unroll
        for (int i = 0; i < 8; ++i) { acc[i][0] = 0.0f; acc[i][1] = 0.0f; }

        if (K > 0) {
            const int k1 = (K > 1) ? 1 : 0;
            float4 ya0 = *(const float4*)&wy[0][8 * yh];
            float4 yb0 = *(const float4*)&wy[0][8 * yh + 4];
            float4 z0  = *(const float4*)&wz[0][4 * zq];
            float  x0v = wxx[0][xi];
            float4 ya1 = *(const float4*)&wy[k1][8 * yh];
            float4 yb1 = *(const float4*)&wy[k1][8 * yh + 4];
            float4 z1  = *(const float4*)&wz[k1][4 * zq];
            float  x1v = wxx[k1][xi];

            for (int k = 0; k < K; ++k) {
                const int kn = (k + 2 < K) ? (k + 2) : (K - 1);
                const float4 ya2 = *(const float4*)&wy[kn][8 * yh];
                const float4 yb2 = *(const float4*)&wy[kn][8 * yh + 4];
                const float4 z2  = *(const float4*)&wz[kn][4 * zq];
                const float  x2v = wxx[kn][xi];

                const float ymax = fmaxf(fmaxf(fmaxf(ya0.x, ya0.y), fmaxf(ya0.z, ya0.w)),
                                         fmaxf(fmaxf(yb0.x, yb0.y), fmaxf(yb0.z, yb0.w)));
                // Per-lane mask; if NO lane in the wave has x0v!=0 (gaussian
                // only touches the other half), hardware execz skips the body.
                if ((x0v != 0.0f) & (ymax != 0.0f)) {
                    const f2 cz0 = {z0.x, z0.y};
                    const f2 cz1 = {z0.z, z0.w};
                    const float p0 = ya0.x * x0v, p1 = ya0.y * x0v;
                    const float p2 = ya0.z * x0v, p3 = ya0.w * x0v;
                    const float p4 = yb0.x * x0v, p5 = yb0.y * x0v;
                    const float p6 = yb0.z * x0v, p7 = yb0.w * x0v;
                    acc[0][0] += p0 * cz0; acc[0][1] += p0 * cz1;
                    acc[1][0] += p1 * cz0; acc[1][1] += p1 * cz1;
                    acc[2][0] += p2 * cz0; acc[2][1] += p2 * cz1;
                    acc[3][0] += p3 * cz0; acc[3][1] += p3 * cz1;
                    acc[4][0] += p4 * cz0; acc[4][1] += p4 * cz1;
                    acc[5][0] += p5 * cz0; acc[5][1] += p5 * cz1;
                    acc[6][0] += p6 * cz0; acc[6][1] += p6 * cz1;
                    acc[7][0] += p7 * cz0; acc[7][1] += p7 * cz1;
                }
                ya0 = ya1; yb0 = yb1; z0 = z1; x0v = x1v;
                ya1 = ya2; yb1 = yb2; z1 = z2; x1v = x2v;
            }
        }

        // Full-line NT stores for this half; fire-and-forget, no barrier ->
        // half-A's drain overlaps half-B's K-loop.
        #pragma unroll
        for (int yy = 0; yy < 8; ++yy) {
            const int y = 8 * yh + yy;
            const size_t lin = (size_t)(vx0 + xi) * (VOLD * VOLD)
                             + (size_t)(vy0 + y) * VOLD + (size_t)(vz0 + 4 * zq);
            nfloat4 v;
            v.x = acc[yy][0].x; v.y = acc[yy][0].y;
            v.z = acc[yy][1].x; v.w = acc[yy][1].y;
            __builtin_nontemporal_store(v, (nfloat4*)&vol[lin]);
        }
    }
}

extern "C" void kernel_launch(void* const* d_in, const int* in_sizes, int n_in,
                              void* d_out, int out_size, void* d_ws, size_t ws_size,
                              hipStream_t stream) {
    const float* centers = (const float*)d_in[0];   // (N,3)
    const float* sigmas  = (const float*)d_in[1];   // (N,)
    const float* intens  = (const float*)d_in[2];   // (N,)
    float* vol = (float*)d_out;
    const int N = in_sizes[1];                      // 4000

    splat_kernel<<<NCELLS, 256, 0, stream>>>(centers, sigmas, intens, vol, N);
}

// Round 12
// 25.573 us; speedup vs baseline: 1.1688x; 1.1688x over previous
//
#include <hip/hip_runtime.h>

#define VOLD 256
// Cell = 16(x) x 16(y) x 32(z); grid 16 x 16 x 8 = 2048 cells, one fused kernel.
#define CXD 16
#define CYD 16
#define CZD 32
#define NCELLS 2048
#define CAP 80

typedef float nfloat4 __attribute__((ext_vector_type(4)));
typedef float f2 __attribute__((ext_vector_type(2)));

__global__ __launch_bounds__(256) void splat_kernel(
    const float* __restrict__ centers, const float* __restrict__ sigmas,
    const float* __restrict__ intens, float* __restrict__ vol, int N)
{
    const int cell = blockIdx.x;
    const int czc = cell & 7;            // 0..7
    const int cyc = (cell >> 3) & 15;    // 0..15
    const int cxc = cell >> 7;           // 0..15
    const int vx0 = cxc * CXD, vy0 = cyc * CYD, vz0 = czc * CZD;
    const int t = threadIdx.x;

    __shared__ int           lcnt;
    __shared__ float4        pc4[CAP];        // cx, cy, cz, sigma
    __shared__ float         pint[CAP];       // intensity
    __shared__ float         wx[CAP][CXD];    // intensity folded in
    __shared__ float         wy[CAP][CYD];
    __shared__ float         wz[CAP][CZD];
    __shared__ unsigned char wlist[4][CAP];   // per-wave compacted k-lists
    // total ~22.4 KB -> 7 blocks/CU, 28 waves/CU

    if (t == 0) lcnt = 0;
    __syncthreads();

    // ---- Scan: 4-gaussian packs, 4 x dwordx4 loads per pack (R10). ----
    const float axh = (float)(vx0 + CXD) + 0.5f, axl = (float)vx0 - 0.5f;
    const float ayh = (float)(vy0 + CYD) + 0.5f, ayl = (float)vy0 - 0.5f;
    const float azh = (float)(vz0 + CZD) + 0.5f, azl = (float)vz0 - 0.5f;

    const float4* c4 = (const float4*)centers;
    const float4* s4 = (const float4*)sigmas;
    const int npack = N >> 2;
    for (int i = t; i < npack; i += 256) {
        const float4 f0  = c4[3 * i];
        const float4 f1  = c4[3 * i + 1];
        const float4 f2v = c4[3 * i + 2];
        const float4 sg4 = s4[i];
        const float gx[4] = {f0.x, f0.w, f1.z, f2v.y};
        const float gy[4] = {f0.y, f1.x, f1.w, f2v.z};
        const float gz[4] = {f0.z, f1.y, f2v.x, f2v.w};
        const float gs[4] = {sg4.x, sg4.y, sg4.z, sg4.w};
        #pragma unroll
        for (int u = 0; u < 4; ++u) {
            const float m1 = fmaxf(fmaxf(fmaf(gx[u], 255.0f, -axh),
                                         fmaf(gy[u], 255.0f, -ayh)),
                                         fmaf(gz[u], 255.0f, -azh));
            const float m2 = fmaxf(fmaxf(fmaf(-gx[u], 255.0f, axl),
                                         fmaf(-gy[u], 255.0f, ayl)),
                                         fmaf(-gz[u], 255.0f, azl));
            if (fmaxf(m1, m2) < gs[u] * 765.0f) {
                const int p = atomicAdd(&lcnt, 1);
                if (p < CAP) {
                    pc4[p]  = make_float4(gx[u], gy[u], gz[u], gs[u]);
                    pint[p] = intens[4 * i + u];
                }
            }
        }
    }
    for (int g = (npack << 2) + t; g < N; g += 256) {   // tail, robustness
        const float cx = centers[3 * g], cy = centers[3 * g + 1], cz = centers[3 * g + 2];
        const float sg = sigmas[g];
        const float m1 = fmaxf(fmaxf(fmaf(cx, 255.0f, -axh), fmaf(cy, 255.0f, -ayh)),
                               fmaf(cz, 255.0f, -azh));
        const float m2 = fmaxf(fmaxf(fmaf(-cx, 255.0f, axl), fmaf(-cy, 255.0f, ayl)),
                               fmaf(-cz, 255.0f, azl));
        if (fmaxf(m1, m2) < sg * 765.0f) {
            const int p = atomicAdd(&lcnt, 1);
            if (p < CAP) { pc4[p] = make_float4(cx, cy, cz, sg); pint[p] = intens[g]; }
        }
    }
    __syncthreads();
    const int K = min(lcnt, CAP);

    // ---- Weights (float-domain validity == reference's floor/int logic). ----
    for (int i = t; i < K * CXD; i += 256) {
        const int g = i >> 4, o = i & 15;
        const float4 p = pc4[g];
        const float cn = p.x, sig = p.w;
        const float cv = cn * 255.0f, cut = 3.0f * sig * 255.0f;
        const float fi = (float)(vx0 + o);
        float wv = 0.0f;
        if ((fi + 1.0f > cv - cut) && (fi <= fminf(cv + cut, 255.0f))) {
            const float d = fi * (1.0f / 255.0f) - cn;
            wv = __expf(-d * d * (0.5f / (sig * sig))) * pint[g];
        }
        wx[g][o] = wv;
    }
    for (int i = t; i < K * CYD; i += 256) {
        const int g = i >> 4, o = i & 15;
        const float4 p = pc4[g];
        const float cn = p.y, sig = p.w;
        const float cv = cn * 255.0f, cut = 3.0f * sig * 255.0f;
        const float fi = (float)(vy0 + o);
        float wv = 0.0f;
        if ((fi + 1.0f > cv - cut) && (fi <= fminf(cv + cut, 255.0f))) {
            const float d = fi * (1.0f / 255.0f) - cn;
            wv = __expf(-d * d * (0.5f / (sig * sig)));
        }
        wy[g][o] = wv;
    }
    for (int i = t; i < K * CZD; i += 256) {
        const int g = i >> 5, o = i & 31;
        const float4 p = pc4[g];
        const float cn = p.z, sig = p.w;
        const float cv = cn * 255.0f, cut = 3.0f * sig * 255.0f;
        const float fi = (float)(vz0 + o);
        float wv = 0.0f;
        if ((fi + 1.0f > cv - cut) && (fi <= fminf(cv + cut, 255.0f))) {
            const float d = fi * (1.0f / 255.0f) - cn;
            wv = __expf(-d * d * (0.5f / (sig * sig)));
        }
        wz[g][o] = wv;
    }
    __syncthreads();

    // ---- Per-wave list compaction: this wave's 8x x 8y footprint. ----
    const int wv_id = t >> 6;            // wave 0..3
    const int lane  = t & 63;
    const float xw0 = (float)(vx0 + 8 * (wv_id & 1));   // wave x-window [xw0, xw0+8)
    const float yw0 = (float)(vy0 + 8 * (wv_id >> 1));  // wave y-window [yw0, yw0+8)

    int Kw = 0;
    for (int j0 = 0; j0 < K; j0 += 64) {
        const int j = j0 + lane;
        bool rel = false;
        if (j < K) {
            const float4 p = pc4[j];
            const float cvx = p.x * 255.0f, cvy = p.y * 255.0f;
            const float cut = p.w * 765.0f;
            // loose (+1 voxel) overlap test vs weight support: false POSITIVES only
            rel = (cvx + cut >= xw0 - 1.0f) && (cvx - cut <= xw0 + 9.0f) &&
                  (cvy + cut >= yw0 - 1.0f) && (cvy - cut <= yw0 + 9.0f);
        }
        const unsigned long long m = __ballot(rel);
        if (rel) {
            const int pos = Kw + __popcll(m & ((1ull << lane) - 1ull));
            wlist[wv_id][pos] = (unsigned char)j;
        }
        Kw += __popcll(m);
    }
    // wlist[wv_id] written & read by the same wave only -> no barrier needed.

    // ---- Accumulate over compacted list: no branch, no masking in body. ----
    const int zq = t & 7;            // z = 4*zq .. 4*zq+3
    const int xi = (t >> 3) & 15;    // x
    const int yh = t >> 7;           // y base = 8*yh

    f2 acc[8][2];                    // [yy][z-pair]
    #pragma unroll
    for (int i = 0; i < 8; ++i) { acc[i][0] = 0.0f; acc[i][1] = 0.0f; }

    if (Kw > 0) {
        const unsigned char* wl = wlist[wv_id];
        const int kd0 = wl[0];
        const int kd1 = wl[(Kw > 1) ? 1 : 0];
        int kI2 = wl[(Kw > 2) ? 2 : (Kw - 1)];

        float4 ya0 = *(const float4*)&wy[kd0][8 * yh];
        float4 yb0 = *(const float4*)&wy[kd0][8 * yh + 4];
        float4 z0  = *(const float4*)&wz[kd0][4 * zq];
        float  x0v = wx[kd0][xi];
        float4 ya1 = *(const float4*)&wy[kd1][8 * yh];
        float4 yb1 = *(const float4*)&wy[kd1][8 * yh + 4];
        float4 z1  = *(const float4*)&wz[kd1][4 * zq];
        float  x1v = wx[kd1][xi];

        #pragma unroll 2
        for (int j = 0; j < Kw; ++j) {
            const int kI3 = wl[(j + 3 < Kw) ? (j + 3) : (Kw - 1)];  // index prefetch
            const float4 ya2 = *(const float4*)&wy[kI2][8 * yh];    // data prefetch
            const float4 yb2 = *(const float4*)&wy[kI2][8 * yh + 4];
            const float4 z2  = *(const float4*)&wz[kI2][4 * zq];
            const float  x2v = wx[kI2][xi];

            const f2 cz0 = {z0.x, z0.y};
            const f2 cz1 = {z0.z, z0.w};
            const float p0 = ya0.x * x0v, p1 = ya0.y * x0v;
            const float p2 = ya0.z * x0v, p3 = ya0.w * x0v;
            const float p4 = yb0.x * x0v, p5 = yb0.y * x0v;
            const float p6 = yb0.z * x0v, p7 = yb0.w * x0v;
            acc[0][0] += p0 * cz0; acc[0][1] += p0 * cz1;
            acc[1][0] += p1 * cz0; acc[1][1] += p1 * cz1;
            acc[2][0] += p2 * cz0; acc[2][1] += p2 * cz1;
            acc[3][0] += p3 * cz0; acc[3][1] += p3 * cz1;
            acc[4][0] += p4 * cz0; acc[4][1] += p4 * cz1;
            acc[5][0] += p5 * cz0; acc[5][1] += p5 * cz1;
            acc[6][0] += p6 * cz0; acc[6][1] += p6 * cz1;
            acc[7][0] += p7 * cz0; acc[7][1] += p7 * cz1;

            ya0 = ya1; yb0 = yb1; z0 = z1; x0v = x1v;
            ya1 = ya2; yb1 = yb2; z1 = z2; x1v = x2v;
            kI2 = kI3;
        }
    }

    // ---- Full-line nontemporal stores: 8 x dwordx4 per thread. ----
    #pragma unroll
    for (int yy = 0; yy < 8; ++yy) {
        const int y = 8 * yh + yy;
        const size_t lin = (size_t)(vx0 + xi) * (VOLD * VOLD)
                         + (size_t)(vy0 + y) * VOLD + (size_t)(vz0 + 4 * zq);
        nfloat4 v;
        v.x = acc[yy][0].x; v.y = acc[yy][0].y;
        v.z = acc[yy][1].x; v.w = acc[yy][1].y;
        __builtin_nontemporal_store(v, (nfloat4*)&vol[lin]);
    }
}

extern "C" void kernel_launch(void* const* d_in, const int* in_sizes, int n_in,
                              void* d_out, int out_size, void* d_ws, size_t ws_size,
                              hipStream_t stream) {
    const float* centers = (const float*)d_in[0];   // (N,3)
    const float* sigmas  = (const float*)d_in[1];   // (N,)
    const float* intens  = (const float*)d_in[2];   // (N,)
    float* vol = (float*)d_out;
    const int N = in_sizes[1];                      // 4000

    splat_kernel<<<NCELLS, 256, 0, stream>>>(centers, sigmas, intens, vol, N);
}

// Round 13
// 25.567 us; speedup vs baseline: 1.1691x; 1.0002x over previous
//
#include <hip/hip_runtime.h>

#define VOLD 256
// Cell = 16(x) x 16(y) x 32(z); 2048 cells total.
// 1024 blocks x 2 cells each: cell A's NT-store drain overlaps cell B's
// compute (raw lgkm-only barriers -> no vmcnt drain mid-kernel).
#define CXD 16
#define CYD 16
#define CZD 32
#define NBLK 1024
#define CAP 80

typedef float nfloat4 __attribute__((ext_vector_type(4)));
typedef float f2 __attribute__((ext_vector_type(2)));

// Raw workgroup barrier WITHOUT vmcnt drain: LDS-ordering only.
#define LGKM_BAR() do {                                     \
    asm volatile("s_waitcnt lgkmcnt(0)" ::: "memory");      \
    __builtin_amdgcn_sched_barrier(0);                      \
    __builtin_amdgcn_s_barrier();                           \
    __builtin_amdgcn_sched_barrier(0);                      \
  } while (0)

__global__ __launch_bounds__(256) void splat_kernel(
    const float* __restrict__ centers, const float* __restrict__ sigmas,
    const float* __restrict__ intens, float* __restrict__ vol, int N)
{
    const int t = threadIdx.x;

    __shared__ int           lcnt[2];         // per-cell counters (no reset race)
    __shared__ float4        pc4[CAP];        // cx, cy, cz, sigma
    __shared__ float         pint[CAP];       // intensity
    __shared__ float         wx[CAP][CXD];    // intensity folded in
    __shared__ float         wy[CAP][CYD];
    __shared__ float         wz[CAP][CZD];
    __shared__ unsigned char wlist[4][CAP];   // per-wave compacted k-lists
    // ~22.4 KB

    if (t < 2) lcnt[t] = 0;

    const float4* c4 = (const float4*)centers;
    const float4* s4 = (const float4*)sigmas;
    const int npack = N >> 2;

    #pragma unroll
    for (int cc = 0; cc < 2; ++cc) {
        const int cell = blockIdx.x + cc * NBLK;
        const int czc = cell & 7;            // 0..7
        const int cyc = (cell >> 3) & 15;    // 0..15
        const int cxc = cell >> 7;           // 0..15
        const int vx0 = cxc * CXD, vy0 = cyc * CYD, vz0 = czc * CZD;

        // cc=0: makes lcnt init visible. cc=1: all waves done reading cell A's
        // LDS (their lgkmcnt drained before joining) -> safe to overwrite.
        LGKM_BAR();

        // ---- Scan: 4-gaussian packs, 4 x dwordx4 loads per pack. ----
        const float axh = (float)(vx0 + CXD) + 0.5f, axl = (float)vx0 - 0.5f;
        const float ayh = (float)(vy0 + CYD) + 0.5f, ayl = (float)vy0 - 0.5f;
        const float azh = (float)(vz0 + CZD) + 0.5f, azl = (float)vz0 - 0.5f;

        for (int i = t; i < npack; i += 256) {
            const float4 f0  = c4[3 * i];
            const float4 f1  = c4[3 * i + 1];
            const float4 f2v = c4[3 * i + 2];
            const float4 sg4 = s4[i];
            const float gx[4] = {f0.x, f0.w, f1.z, f2v.y};
            const float gy[4] = {f0.y, f1.x, f1.w, f2v.z};
            const float gz[4] = {f0.z, f1.y, f2v.x, f2v.w};
            const float gs[4] = {sg4.x, sg4.y, sg4.z, sg4.w};
            #pragma unroll
            for (int u = 0; u < 4; ++u) {
                const float m1 = fmaxf(fmaxf(fmaf(gx[u], 255.0f, -axh),
                                             fmaf(gy[u], 255.0f, -ayh)),
                                             fmaf(gz[u], 255.0f, -azh));
                const float m2 = fmaxf(fmaxf(fmaf(-gx[u], 255.0f, axl),
                                             fmaf(-gy[u], 255.0f, ayl)),
                                             fmaf(-gz[u], 255.0f, azl));
                if (fmaxf(m1, m2) < gs[u] * 765.0f) {
                    const int p = atomicAdd(&lcnt[cc], 1);
                    if (p < CAP) {
                        pc4[p]  = make_float4(gx[u], gy[u], gz[u], gs[u]);
                        pint[p] = intens[4 * i + u];
                    }
                }
            }
        }
        for (int g = (npack << 2) + t; g < N; g += 256) {   // tail, robustness
            const float cx = centers[3 * g], cy = centers[3 * g + 1], cz = centers[3 * g + 2];
            const float sg = sigmas[g];
            const float m1 = fmaxf(fmaxf(fmaf(cx, 255.0f, -axh), fmaf(cy, 255.0f, -ayh)),
                                   fmaf(cz, 255.0f, -azh));
            const float m2 = fmaxf(fmaxf(fmaf(-cx, 255.0f, axl), fmaf(-cy, 255.0f, ayl)),
                                   fmaf(-cz, 255.0f, azl));
            if (fmaxf(m1, m2) < sg * 765.0f) {
                const int p = atomicAdd(&lcnt[cc], 1);
                if (p < CAP) { pc4[p] = make_float4(cx, cy, cz, sg); pint[p] = intens[g]; }
            }
        }
        LGKM_BAR();
        const int K = min(lcnt[cc], CAP);

        // ---- Weights (float-domain validity == reference's floor/int logic). ----
        for (int i = t; i < K * CXD; i += 256) {
            const int g = i >> 4, o = i & 15;
            const float4 p = pc4[g];
            const float cn = p.x, sig = p.w;
            const float cv = cn * 255.0f, cut = 3.0f * sig * 255.0f;
            const float fi = (float)(vx0 + o);
            float wv = 0.0f;
            if ((fi + 1.0f > cv - cut) && (fi <= fminf(cv + cut, 255.0f))) {
                const float d = fi * (1.0f / 255.0f) - cn;
                wv = __expf(-d * d * (0.5f / (sig * sig))) * pint[g];
            }
            wx[g][o] = wv;
        }
        for (int i = t; i < K * CYD; i += 256) {
            const int g = i >> 4, o = i & 15;
            const float4 p = pc4[g];
            const float cn = p.y, sig = p.w;
            const float cv = cn * 255.0f, cut = 3.0f * sig * 255.0f;
            const float fi = (float)(vy0 + o);
            float wv = 0.0f;
            if ((fi + 1.0f > cv - cut) && (fi <= fminf(cv + cut, 255.0f))) {
                const float d = fi * (1.0f / 255.0f) - cn;
                wv = __expf(-d * d * (0.5f / (sig * sig)));
            }
            wy[g][o] = wv;
        }
        for (int i = t; i < K * CZD; i += 256) {
            const int g = i >> 5, o = i & 31;
            const float4 p = pc4[g];
            const float cn = p.z, sig = p.w;
            const float cv = cn * 255.0f, cut = 3.0f * sig * 255.0f;
            const float fi = (float)(vz0 + o);
            float wv = 0.0f;
            if ((fi + 1.0f > cv - cut) && (fi <= fminf(cv + cut, 255.0f))) {
                const float d = fi * (1.0f / 255.0f) - cn;
                wv = __expf(-d * d * (0.5f / (sig * sig)));
            }
            wz[g][o] = wv;
        }
        LGKM_BAR();

        // ---- Per-wave list compaction (8x x 8y wave footprint). ----
        const int wv_id = t >> 6;
        const int lane  = t & 63;
        const float xw0 = (float)(vx0 + 8 * (wv_id & 1));
        const float yw0 = (float)(vy0 + 8 * (wv_id >> 1));

        int Kw = 0;
        for (int j0 = 0; j0 < K; j0 += 64) {
            const int j = j0 + lane;
            bool rel = false;
            if (j < K) {
                const float4 p = pc4[j];
                const float cvx = p.x * 255.0f, cvy = p.y * 255.0f;
                const float cut = p.w * 765.0f;
                rel = (cvx + cut >= xw0 - 1.0f) && (cvx - cut <= xw0 + 9.0f) &&
                      (cvy + cut >= yw0 - 1.0f) && (cvy - cut <= yw0 + 9.0f);
            }
            const unsigned long long m = __ballot(rel);
            if (rel) {
                const int pos = Kw + __popcll(m & ((1ull << lane) - 1ull));
                wlist[wv_id][pos] = (unsigned char)j;
            }
            Kw += __popcll(m);
        }
        // wlist[wv_id] written & read by the same wave only -> no barrier.

        // ---- Accumulate over compacted list (branch-free body). ----
        const int zq = t & 7;
        const int xi = (t >> 3) & 15;
        const int yh = t >> 7;

        f2 acc[8][2];
        #pragma unroll
        for (int i = 0; i < 8; ++i) { acc[i][0] = 0.0f; acc[i][1] = 0.0f; }

        if (Kw > 0) {
            const unsigned char* wl = wlist[wv_id];
            const int kd0 = wl[0];
            const int kd1 = wl[(Kw > 1) ? 1 : 0];
            int kI2 = wl[(Kw > 2) ? 2 : (Kw - 1)];

            float4 ya0 = *(const float4*)&wy[kd0][8 * yh];
            float4 yb0 = *(const float4*)&wy[kd0][8 * yh + 4];
            float4 z0  = *(const float4*)&wz[kd0][4 * zq];
            float  x0v = wx[kd0][xi];
            float4 ya1 = *(const float4*)&wy[kd1][8 * yh];
            float4 yb1 = *(const float4*)&wy[kd1][8 * yh + 4];
            float4 z1  = *(const float4*)&wz[kd1][4 * zq];
            float  x1v = wx[kd1][xi];

            #pragma unroll 2
            for (int j = 0; j < Kw; ++j) {
                const int kI3 = wl[(j + 3 < Kw) ? (j + 3) : (Kw - 1)];
                const float4 ya2 = *(const float4*)&wy[kI2][8 * yh];
                const float4 yb2 = *(const float4*)&wy[kI2][8 * yh + 4];
                const float4 z2  = *(const float4*)&wz[kI2][4 * zq];
                const float  x2v = wx[kI2][xi];

                const f2 cz0 = {z0.x, z0.y};
                const f2 cz1 = {z0.z, z0.w};
                const float p0 = ya0.x * x0v, p1 = ya0.y * x0v;
                const float p2 = ya0.z * x0v, p3 = ya0.w * x0v;
                const float p4 = yb0.x * x0v, p5 = yb0.y * x0v;
                const float p6 = yb0.z * x0v, p7 = yb0.w * x0v;
                acc[0][0] += p0 * cz0; acc[0][1] += p0 * cz1;
                acc[1][0] += p1 * cz0; acc[1][1] += p1 * cz1;
                acc[2][0] += p2 * cz0; acc[2][1] += p2 * cz1;
                acc[3][0] += p3 * cz0; acc[3][1] += p3 * cz1;
                acc[4][0] += p4 * cz0; acc[4][1] += p4 * cz1;
                acc[5][0] += p5 * cz0; acc[5][1] += p5 * cz1;
                acc[6][0] += p6 * cz0; acc[6][1] += p6 * cz1;
                acc[7][0] += p7 * cz0; acc[7][1] += p7 * cz1;

                ya0 = ya1; yb0 = yb1; z0 = z1; x0v = x1v;
                ya1 = ya2; yb1 = yb2; z1 = z2; x1v = x2v;
                kI2 = kI3;
            }
        }

        // ---- Fire-and-forget full-line NT stores (never vmcnt-waited). ----
        #pragma unroll
        for (int yy = 0; yy < 8; ++yy) {
            const int y = 8 * yh + yy;
            const size_t lin = (size_t)(vx0 + xi) * (VOLD * VOLD)
                             + (size_t)(vy0 + y) * VOLD + (size_t)(vz0 + 4 * zq);
            nfloat4 v;
            v.x = acc[yy][0].x; v.y = acc[yy][0].y;
            v.z = acc[yy][1].x; v.w = acc[yy][1].y;
            __builtin_nontemporal_store(v, (nfloat4*)&vol[lin]);
        }
    }
}

extern "C" void kernel_launch(void* const* d_in, const int* in_sizes, int n_in,
                              void* d_out, int out_size, void* d_ws, size_t ws_size,
                              hipStream_t stream) {
    const float* centers = (const float*)d_in[0];   // (N,3)
    const float* sigmas  = (const float*)d_in[1];   // (N,)
    const float* intens  = (const float*)d_in[2];   // (N,)
    float* vol = (float*)d_out;
    const int N = in_sizes[1];                      // 4000

    splat_kernel<<<NBLK, 256, 0, stream>>>(centers, sigmas, intens, vol, N);
}